// Round 3
// baseline (6792.415 us; speedup 1.0000x reference)
//
#include <hip/hip_runtime.h>
#include <math.h>

#define S_LEN 32
#define B_N   16
#define H_N   1024
#define E_N   256
#define V_N   32000
#define KBEAM 4
#define DIN   1536
#define D2    2560   // DIN + H_N
#define R_N   64     // KBEAM * B_N rows of state
#define NDS   8      // d-slices for gates GEMM
#define DSL   320    // D2 / NDS
#define NB    1000   // logits blocks = V_N/32

__device__ __forceinline__ float sigmf(float x){ return 1.0f/(1.0f+expf(-x)); }
__device__ __forceinline__ bool better(float v1,int i1,float v2,int i2){
  return (v1>v2) || (v1==v2 && i1<i2);
}
// insert candidate (bv,bi) into sorted-desc top-4 (av0 best)
__device__ __forceinline__ void ins4(float bv,int bi,
    float&av0,float&av1,float&av2,float&av3,int&ai0,int&ai1,int&ai2,int&ai3){
  if (better(bv,bi,av3,ai3)){ av3=bv; ai3=bi;
    if (better(av3,ai3,av2,ai2)){ float t=av2;av2=av3;av3=t; int q=ai2;ai2=ai3;ai3=q;
      if (better(av2,ai2,av1,ai1)){ t=av1;av1=av2;av2=t; q=ai1;ai1=ai2;ai2=q;
        if (better(av1,ai1,av0,ai0)){ t=av0;av0=av1;av1=t; q=ai0;ai0=ai1;ai1=q; } } } }
}

// ---- init: x0 = [embed[START] | enc_inputs[0] | enc_outputs[0]] , c0
__global__ __launch_bounds__(256) void k_init(
    const float* __restrict__ enc_h_n, const float* __restrict__ enc_c_n,
    const float* __restrict__ enc_outputs, const float* __restrict__ enc_inputs,
    const float* __restrict__ embed, float* __restrict__ x, float* __restrict__ c){
  int r = blockIdx.x, tid = threadIdx.x, b = r & 15;
  float* xr = x + (size_t)r*D2;
  xr[tid]        = embed[E_N + tid];                 // START token = 1
  xr[E_N + tid]  = enc_inputs[b*E_N + tid];          // t = 0
  #pragma unroll
  for (int q=0;q<4;++q) xr[2*E_N + q*256 + tid] = enc_outputs[b*H_N + q*256 + tid];
  #pragma unroll
  for (int q=0;q<4;++q) xr[DIN + q*256 + tid]   = enc_h_n[b*H_N + q*256 + tid];
  #pragma unroll
  for (int q=0;q<4;++q) c[(size_t)r*H_N + q*256 + tid] = enc_c_n[b*H_N + q*256 + tid];
}

// ---- gates GEMM: gpart[ds][64][4096] partial sums of x[64,2560] @ [w_ih;w_hh]
__global__ __launch_bounds__(256) void k_gates(
    const float* __restrict__ x, const float* __restrict__ w_ih,
    const float* __restrict__ w_hh, float* __restrict__ gpart){
  int jt = blockIdx.x, ds = blockIdx.y, tid = threadIdx.x;
  int hl = tid & 15, rq = tid >> 4;
  int col = jt*16 + hl;
  __shared__ float xs[64*68];
  float a0[4]={0,0,0,0}, a1[4]={0,0,0,0}, a2[4]={0,0,0,0}, a3[4]={0,0,0,0};
  for (int ch=0; ch<5; ++ch){
    int dbase = ds*DSL + ch*64;
    {
      int row = tid >> 2, q = tid & 3;
      const float4* src = (const float4*)(x + (size_t)row*D2 + dbase + q*16);
      float4* dst = (float4*)(&xs[row*68 + q*16]);
      dst[0]=src[0]; dst[1]=src[1]; dst[2]=src[2]; dst[3]=src[3];
    }
    __syncthreads();
    for (int dd=0; dd<64; ++dd){
      int d = dbase + dd;
      const float* wr = (d < DIN) ? (w_ih + (size_t)d*4096)
                                  : (w_hh + (size_t)(d-DIN)*4096);
      float wi = wr[col], wf = wr[1024+col], wg = wr[2048+col], wo = wr[3072+col];
      #pragma unroll
      for (int rr=0;rr<4;++rr){
        float xv = xs[(rq*4+rr)*68 + dd];
        a0[rr] = fmaf(xv, wi, a0[rr]);
        a1[rr] = fmaf(xv, wf, a1[rr]);
        a2[rr] = fmaf(xv, wg, a2[rr]);
        a3[rr] = fmaf(xv, wo, a3[rr]);
      }
    }
    __syncthreads();
  }
  #pragma unroll
  for (int rr=0;rr<4;++rr){
    size_t base = ((size_t)ds*R_N + (rq*4+rr))*4096;
    gpart[base + col]        = a0[rr];
    gpart[base + 1024 + col] = a1[rr];
    gpart[base + 2048 + col] = a2[rr];
    gpart[base + 3072 + col] = a3[rr];
  }
}

// ---- LSTM: sum partials + bias, cell update; h2 -> xn[.,1536:] and h2t[1024][64]
__global__ __launch_bounds__(256) void k_lstm(
    const float* __restrict__ gpart, const float* __restrict__ b_lstm,
    float* __restrict__ c, float* __restrict__ xn, float* __restrict__ h2t){
  int r = blockIdx.x, tid = threadIdx.x;
  #pragma unroll
  for (int it=0; it<4; ++it){
    int j = it*256 + tid;
    float gi = b_lstm[j], gf = b_lstm[1024+j], gg = b_lstm[2048+j], go = b_lstm[3072+j];
    #pragma unroll
    for (int ds=0; ds<NDS; ++ds){
      size_t base = ((size_t)ds*R_N + r)*4096;
      gi += gpart[base + j];      gf += gpart[base + 1024 + j];
      gg += gpart[base + 2048+j]; go += gpart[base + 3072 + j];
    }
    float cv = c[(size_t)r*H_N + j];
    float c2 = sigmf(gf)*cv + sigmf(gi)*tanhf(gg);
    float h2 = sigmf(go)*tanhf(c2);
    c[(size_t)r*H_N + j] = c2;
    xn[(size_t)r*D2 + DIN + j] = h2;
    h2t[(size_t)j*R_N + r] = h2;
  }
}

// ---- logits GEMM + fused softmax stats & top-4.
// 1000 blocks x 256 threads; block = 32 cols x 64 rows; wave = 8 cols x 64 rows.
// lane = state row; weights wave-uniform float4 loads, double-buffered depth-1.
#define LOADW(W, dd) { const float* wr_ = wp + (size_t)(dd)*V_N; \
  W[0]=*(const float4*)(wr_);                 W[1]=*(const float4*)(wr_+4); \
  W[2]=*(const float4*)(wr_+(size_t)V_N);     W[3]=*(const float4*)(wr_+(size_t)V_N+4); \
  W[4]=*(const float4*)(wr_+2*(size_t)V_N);   W[5]=*(const float4*)(wr_+2*(size_t)V_N+4); \
  W[6]=*(const float4*)(wr_+3*(size_t)V_N);   W[7]=*(const float4*)(wr_+3*(size_t)V_N+4); }
#define LOADH(H, dd) { H[0]=hp[(size_t)(dd)*64];   H[1]=hp[(size_t)((dd)+1)*64]; \
                       H[2]=hp[(size_t)((dd)+2)*64]; H[3]=hp[(size_t)((dd)+3)*64]; }
#define COMP(W, H) { \
  _Pragma("unroll") \
  for (int r_=0;r_<4;++r_){ \
    float hv_ = H[r_]; float4 lo_ = W[2*r_], hi_ = W[2*r_+1]; \
    acc[0]=fmaf(hv_,lo_.x,acc[0]); acc[1]=fmaf(hv_,lo_.y,acc[1]); \
    acc[2]=fmaf(hv_,lo_.z,acc[2]); acc[3]=fmaf(hv_,lo_.w,acc[3]); \
    acc[4]=fmaf(hv_,hi_.x,acc[4]); acc[5]=fmaf(hv_,hi_.y,acc[5]); \
    acc[6]=fmaf(hv_,hi_.z,acc[6]); acc[7]=fmaf(hv_,hi_.w,acc[7]); } }

__global__ __launch_bounds__(256) void k_logits(
    const float* __restrict__ h2t, const float* __restrict__ w_out,
    const float* __restrict__ b_out,
    float* __restrict__ pm, float* __restrict__ pz,
    float* __restrict__ pv, int* __restrict__ pi){
  int tid = threadIdx.x;
  int lane = tid & 63;
  int wv = __builtin_amdgcn_readfirstlane(tid >> 6);
  int cb = blockIdx.x * 32;
  int c0 = cb + wv*8;
  float acc[8];
  #pragma unroll
  for (int j=0;j<8;++j) acc[j]=0.f;
  const float* hp = h2t + lane;
  const float* wp = w_out + c0;

  float4 W0[8], W1[8];
  float  H0[4], H1[4];
  LOADW(W0, 0) LOADH(H0, 0)
  for (int dd=0; dd<H_N; dd+=8){
    LOADW(W1, dd+4) LOADH(H1, dd+4)
    COMP(W0, H0)
    int nd = (dd+8 < H_N) ? dd+8 : 0;
    LOADW(W0, nd) LOADH(H0, nd)
    COMP(W1, H1)
  }

  // per-thread stats over its 8 cols (row = lane)
  float tv0=-INFINITY,tv1=-INFINITY,tv2=-INFINITY,tv3=-INFINITY;
  int ti0=0x7fffffff,ti1=0x7fffffff,ti2=0x7fffffff,ti3=0x7fffffff;
  #pragma unroll
  for (int j=0;j<8;++j){
    float v = acc[j] + b_out[c0+j];
    acc[j] = v;
    ins4(v, c0+j, tv0,tv1,tv2,tv3, ti0,ti1,ti2,ti3);
  }
  float z = 0.f;
  #pragma unroll
  for (int j=0;j<8;++j) z += expf(acc[j]-tv0);  // tv0 == local max

  __shared__ float sZ[256], sV4[256*4];
  __shared__ int   sI4[256*4];
  sZ[tid]=z;
  sV4[tid*4+0]=tv0; sV4[tid*4+1]=tv1; sV4[tid*4+2]=tv2; sV4[tid*4+3]=tv3;
  sI4[tid*4+0]=ti0; sI4[tid*4+1]=ti1; sI4[tid*4+2]=ti2; sI4[tid*4+3]=ti3;
  __syncthreads();
  if (tid < 64){
    float m = sV4[tid*4], zz = sZ[tid];
    float av0=sV4[tid*4],av1=sV4[tid*4+1],av2=sV4[tid*4+2],av3=sV4[tid*4+3];
    int   ai0=sI4[tid*4],ai1=sI4[tid*4+1],ai2=sI4[tid*4+2],ai3=sI4[tid*4+3];
    #pragma unroll
    for (int o=1;o<4;++o){
      int f = o*64 + tid;
      float mf = sV4[f*4];
      float M = fmaxf(m, mf);
      zz = zz*expf(m-M) + sZ[f]*expf(mf-M);
      m = M;
      #pragma unroll
      for (int q=0;q<4;++q)
        ins4(sV4[f*4+q], sI4[f*4+q], av0,av1,av2,av3, ai0,ai1,ai2,ai3);
    }
    size_t base = (size_t)tid*NB + blockIdx.x;   // row-major [row][block]
    pm[base]=m; pz[base]=zz;
    pv[base*4+0]=av0; pv[base*4+1]=av1; pv[base*4+2]=av2; pv[base*4+3]=av3;
    pi[base*4+0]=ai0; pi[base*4+1]=ai1; pi[base*4+2]=ai2; pi[base*4+3]=ai3;
  }
}

// ---- final: reduce NB partials per row, joint top-4 per b, write out, next-x.
__global__ __launch_bounds__(256) void k_final(
    const float* __restrict__ pm, const float* __restrict__ pz,
    const float* __restrict__ pv, const int* __restrict__ pi,
    float* __restrict__ scores, int* __restrict__ out, int t,
    float* __restrict__ xn,
    const float* __restrict__ enc_inputs, const float* __restrict__ enc_outputs,
    const float* __restrict__ embed){
  int b = blockIdx.x, tid = threadIdx.x;
  __shared__ float sm[256], sz[256], stv[1024];
  __shared__ int   sti[1024];
  __shared__ float fM[KBEAM], fZ[KBEAM], fV[16];
  __shared__ int   fI[16], sw[KBEAM];
  int nk = (t==0) ? 1 : KBEAM;
  for (int k=0;k<nk;++k){
    size_t rb = (size_t)(k*B_N + b)*NB;
    float m=-INFINITY, z=0.f;
    float av0=-INFINITY,av1=-INFINITY,av2=-INFINITY,av3=-INFINITY;
    int   ai0=0x7fffffff,ai1=0x7fffffff,ai2=0x7fffffff,ai3=0x7fffffff;
    for (int p0=tid; p0<NB; p0+=256){
      size_t p = rb + p0;
      float mf = pm[p];
      float M = fmaxf(m, mf);
      z = z*expf(m-M) + pz[p]*expf(mf-M);
      m = M;
      #pragma unroll
      for (int q=0;q<4;++q)
        ins4(pv[p*4+q], pi[p*4+q], av0,av1,av2,av3, ai0,ai1,ai2,ai3);
    }
    sm[tid]=m; sz[tid]=z;
    stv[tid*4+0]=av0; stv[tid*4+1]=av1; stv[tid*4+2]=av2; stv[tid*4+3]=av3;
    sti[tid*4+0]=ai0; sti[tid*4+1]=ai1; sti[tid*4+2]=ai2; sti[tid*4+3]=ai3;
    __syncthreads();
    for (int off=128; off>0; off>>=1){
      if (tid<off){
        float ma=sm[tid], mb=sm[tid+off];
        float za=sz[tid], zb=sz[tid+off];
        float M = fmaxf(ma,mb);
        sz[tid] = za*expf(ma-M) + zb*expf(mb-M);
        sm[tid] = M;
        float bv0=stv[tid*4],bv1=stv[tid*4+1],bv2=stv[tid*4+2],bv3=stv[tid*4+3];
        int   bi0=sti[tid*4],bi1=sti[tid*4+1],bi2=sti[tid*4+2],bi3=sti[tid*4+3];
        #pragma unroll
        for (int q=0;q<4;++q)
          ins4(stv[(tid+off)*4+q], sti[(tid+off)*4+q],
               bv0,bv1,bv2,bv3, bi0,bi1,bi2,bi3);
        stv[tid*4]=bv0; stv[tid*4+1]=bv1; stv[tid*4+2]=bv2; stv[tid*4+3]=bv3;
        sti[tid*4]=bi0; sti[tid*4+1]=bi1; sti[tid*4+2]=bi2; sti[tid*4+3]=bi3;
      }
      __syncthreads();
    }
    if (tid==0){
      fM[k]=sm[0]; fZ[k]=sz[0];
      fV[k*4+0]=stv[0]; fV[k*4+1]=stv[1]; fV[k*4+2]=stv[2]; fV[k*4+3]=stv[3];
      fI[k*4+0]=sti[0]; fI[k*4+1]=sti[1]; fI[k*4+2]=sti[2]; fI[k*4+3]=sti[3];
    }
    __syncthreads();
  }
  if (tid==0){
    if (t==0){
      #pragma unroll
      for (int j=0;j<4;++j){
        float p = expf(fV[j]-fM[0])/fZ[0];
        scores[b*4+j] = p;
        out[j*(B_N*S_LEN) + b*S_LEN] = fI[j];
        sw[j] = fI[j];
      }
    } else {
      float cv[16]; int cj[16];
      for (int k=0;k<4;++k){
        float s = scores[b*4+k];
        #pragma unroll
        for (int j=0;j<4;++j){
          cv[k*4+j] = expf(fV[k*4+j]-fM[k])/fZ[k]*s;
          cj[k*4+j] = k*V_N + fI[k*4+j];
        }
      }
      bool used[16];
      for (int i=0;i<16;++i) used[i]=false;
      for (int rank=0;rank<4;++rank){
        int best=-1;
        for (int i=0;i<16;++i){
          if (used[i]) continue;
          if (best<0 || cv[i]>cv[best] || (cv[i]==cv[best] && cj[i]<cj[best])) best=i;
        }
        used[best]=true;
        out[rank*(B_N*S_LEN) + b*S_LEN + t] = cj[best];
        sw[rank] = cj[best] % V_N;
      }
    }
  }
  __syncthreads();
  if (t < S_LEN-1){
    const float* ein = enc_inputs  + (size_t)(t+1)*B_N*E_N + (size_t)b*E_N;
    const float* eo  = enc_outputs + (size_t)(t+1)*B_N*H_N + (size_t)b*H_N;
    #pragma unroll
    for (int j=0;j<KBEAM;++j){
      float* xr = xn + (size_t)(j*B_N + b)*D2;
      const float* em = embed + (size_t)sw[j]*E_N;
      xr[tid]       = em[tid];
      xr[E_N + tid] = ein[tid];
      #pragma unroll
      for (int q=0;q<4;++q) xr[2*E_N + q*256 + tid] = eo[q*256 + tid];
    }
  }
}

extern "C" void kernel_launch(void* const* d_in, const int* in_sizes, int n_in,
                              void* d_out, int out_size, void* d_ws, size_t ws_size,
                              hipStream_t stream) {
  (void)in_sizes; (void)n_in; (void)out_size; (void)ws_size;
  const float* enc_h_n     = (const float*)d_in[0];
  const float* enc_c_n     = (const float*)d_in[1];
  const float* enc_outputs = (const float*)d_in[2];
  const float* enc_inputs  = (const float*)d_in[3];
  const float* embed       = (const float*)d_in[4];
  const float* w_ih        = (const float*)d_in[5];
  const float* w_hh        = (const float*)d_in[6];
  const float* b_lstm      = (const float*)d_in[7];
  const float* w_out       = (const float*)d_in[8];
  const float* b_out       = (const float*)d_in[9];
  int* out = (int*)d_out;

  float* ws = (float*)d_ws;
  float* xA     = ws;                        // 64*2560
  float* xB     = xA + (size_t)R_N*D2;       // 64*2560
  float* cbuf   = xB + (size_t)R_N*D2;       // 64*1024
  float* h2t    = cbuf + (size_t)R_N*H_N;    // 1024*64
  float* gpart  = h2t + (size_t)H_N*R_N;     // 8*64*4096 (2,097,152 floats)
  // partial-stat buffers alias the gpart region (disjoint lifetimes within a step)
  float* pm     = gpart;                     // 64*NB
  float* pz     = pm + (size_t)R_N*NB;       // 64*NB
  float* pv     = pz + (size_t)R_N*NB;       // 64*NB*4
  int*   pi     = (int*)(pv + (size_t)R_N*NB*4); // 64*NB*4 ints
  float* scoresb= gpart + (size_t)NDS*R_N*4096;  // 64 floats, past gpart

  k_init<<<R_N, 256, 0, stream>>>(enc_h_n, enc_c_n, enc_outputs, enc_inputs, embed, xA, cbuf);

  for (int t=0; t<S_LEN; ++t){
    float* xc = (t & 1) ? xB : xA;
    float* xn = (t & 1) ? xA : xB;
    k_gates <<<dim3(64, NDS), 256, 0, stream>>>(xc, w_ih, w_hh, gpart);
    k_lstm  <<<R_N, 256, 0, stream>>>(gpart, b_lstm, cbuf, xn, h2t);
    k_logits<<<NB, 256, 0, stream>>>(h2t, w_out, b_out, pm, pz, pv, pi);
    k_final <<<B_N, 256, 0, stream>>>(pm, pz, pv, pi, scoresb, out, t, xn,
                                      enc_inputs, enc_outputs, embed);
  }
}

// Round 4
// 6055.464 us; speedup vs baseline: 1.1217x; 1.1217x over previous
//
#include <hip/hip_runtime.h>
#include <math.h>

#define S_LEN 32
#define B_N   16
#define H_N   1024
#define E_N   256
#define V_N   32000
#define KBEAM 4
#define DIN   1536
#define D2    2560   // DIN + H_N
#define R_N   64     // KBEAM * B_N rows of state
#define NDS   8      // d-slices for gates GEMM
#define DSL   320    // D2 / NDS
#define NB    500    // logits blocks = V_N/64

__device__ __forceinline__ float sigmf(float x){ return 1.0f/(1.0f+expf(-x)); }
__device__ __forceinline__ bool better(float v1,int i1,float v2,int i2){
  return (v1>v2) || (v1==v2 && i1<i2);
}
// insert candidate (bv,bi) into sorted-desc top-4 (av0 best)
__device__ __forceinline__ void ins4(float bv,int bi,
    float&av0,float&av1,float&av2,float&av3,int&ai0,int&ai1,int&ai2,int&ai3){
  if (better(bv,bi,av3,ai3)){ av3=bv; ai3=bi;
    if (better(av3,ai3,av2,ai2)){ float t=av2;av2=av3;av3=t; int q=ai2;ai2=ai3;ai3=q;
      if (better(av2,ai2,av1,ai1)){ t=av1;av1=av2;av2=t; q=ai1;ai1=ai2;ai2=q;
        if (better(av1,ai1,av0,ai0)){ t=av0;av0=av1;av1=t; q=ai0;ai0=ai1;ai1=q; } } } }
}

// ---- init: x0 = [embed[START] | enc_inputs[0] | enc_outputs[0]] , c0
__global__ __launch_bounds__(256) void k_init(
    const float* __restrict__ enc_h_n, const float* __restrict__ enc_c_n,
    const float* __restrict__ enc_outputs, const float* __restrict__ enc_inputs,
    const float* __restrict__ embed, float* __restrict__ x, float* __restrict__ c){
  int r = blockIdx.x, tid = threadIdx.x, b = r & 15;
  float* xr = x + (size_t)r*D2;
  xr[tid]        = embed[E_N + tid];                 // START token = 1
  xr[E_N + tid]  = enc_inputs[b*E_N + tid];          // t = 0
  #pragma unroll
  for (int q=0;q<4;++q) xr[2*E_N + q*256 + tid] = enc_outputs[b*H_N + q*256 + tid];
  #pragma unroll
  for (int q=0;q<4;++q) xr[DIN + q*256 + tid]   = enc_h_n[b*H_N + q*256 + tid];
  #pragma unroll
  for (int q=0;q<4;++q) c[(size_t)r*H_N + q*256 + tid] = enc_c_n[b*H_N + q*256 + tid];
}

// ---- gates GEMM: gpart[ds][64][4096] partial sums of x[64,2560] @ [w_ih;w_hh]
__global__ __launch_bounds__(256) void k_gates(
    const float* __restrict__ x, const float* __restrict__ w_ih,
    const float* __restrict__ w_hh, float* __restrict__ gpart){
  int jt = blockIdx.x, ds = blockIdx.y, tid = threadIdx.x;
  int hl = tid & 15, rq = tid >> 4;
  int col = jt*16 + hl;
  __shared__ float xs[64*68];
  float a0[4]={0,0,0,0}, a1[4]={0,0,0,0}, a2[4]={0,0,0,0}, a3[4]={0,0,0,0};
  for (int ch=0; ch<5; ++ch){
    int dbase = ds*DSL + ch*64;
    {
      int row = tid >> 2, q = tid & 3;
      const float4* src = (const float4*)(x + (size_t)row*D2 + dbase + q*16);
      float4* dst = (float4*)(&xs[row*68 + q*16]);
      dst[0]=src[0]; dst[1]=src[1]; dst[2]=src[2]; dst[3]=src[3];
    }
    __syncthreads();
    for (int dd=0; dd<64; ++dd){
      int d = dbase + dd;
      const float* wr = (d < DIN) ? (w_ih + (size_t)d*4096)
                                  : (w_hh + (size_t)(d-DIN)*4096);
      float wi = wr[col], wf = wr[1024+col], wg = wr[2048+col], wo = wr[3072+col];
      #pragma unroll
      for (int rr=0;rr<4;++rr){
        float xv = xs[(rq*4+rr)*68 + dd];
        a0[rr] = fmaf(xv, wi, a0[rr]);
        a1[rr] = fmaf(xv, wf, a1[rr]);
        a2[rr] = fmaf(xv, wg, a2[rr]);
        a3[rr] = fmaf(xv, wo, a3[rr]);
      }
    }
    __syncthreads();
  }
  #pragma unroll
  for (int rr=0;rr<4;++rr){
    size_t base = ((size_t)ds*R_N + (rq*4+rr))*4096;
    gpart[base + col]        = a0[rr];
    gpart[base + 1024 + col] = a1[rr];
    gpart[base + 2048 + col] = a2[rr];
    gpart[base + 3072 + col] = a3[rr];
  }
}

// ---- LSTM: sum partials + bias, cell update; h2 -> xn[.,1536:] and h2t[1024][64]
__global__ __launch_bounds__(256) void k_lstm(
    const float* __restrict__ gpart, const float* __restrict__ b_lstm,
    float* __restrict__ c, float* __restrict__ xn, float* __restrict__ h2t){
  int r = blockIdx.x, tid = threadIdx.x;
  #pragma unroll
  for (int it=0; it<4; ++it){
    int j = it*256 + tid;
    float gi = b_lstm[j], gf = b_lstm[1024+j], gg = b_lstm[2048+j], go = b_lstm[3072+j];
    #pragma unroll
    for (int ds=0; ds<NDS; ++ds){
      size_t base = ((size_t)ds*R_N + r)*4096;
      gi += gpart[base + j];      gf += gpart[base + 1024 + j];
      gg += gpart[base + 2048+j]; go += gpart[base + 3072 + j];
    }
    float cv = c[(size_t)r*H_N + j];
    float c2 = sigmf(gf)*cv + sigmf(gi)*tanhf(gg);
    float h2 = sigmf(go)*tanhf(c2);
    c[(size_t)r*H_N + j] = c2;
    xn[(size_t)r*D2 + DIN + j] = h2;
    h2t[(size_t)j*R_N + r] = h2;
  }
}

// ---- logits GEMM + fused softmax stats & top-4 (LDS-staged, register-tiled).
// 500 blocks x 256 thr. Block tile: 64 cols x 64 rows. Thread: 4 cols x 4 rows.
// Chunks of 32 dd; W[32][64] + h[32][64] staged in LDS via coalesced float4
// loads, reg-staged double buffer (loads for chunk k+1 in flight during
// compute of chunk k).
__global__ __launch_bounds__(256) void k_logits(
    const float* __restrict__ h2t, const float* __restrict__ w_out,
    const float* __restrict__ b_out,
    float* __restrict__ pm, float* __restrict__ pz,
    float* __restrict__ pv, int* __restrict__ pi){
  int tid = threadIdx.x;
  int cx  = tid & 15;         // col group: cols cb + cx*4 .. +3
  int ry  = tid >> 4;         // row group: rows ry*4 .. +3
  int cb  = blockIdx.x * 64;
  int sdd = tid >> 4, seg = tid & 15;   // staging map: 16 dd-rows x 16 segs

  __shared__ float Wt[32][64];
  __shared__ float Ht[32][64];

  float acc[4][4];
  #pragma unroll
  for (int cc=0;cc<4;++cc)
    #pragma unroll
    for (int rr=0;rr<4;++rr) acc[cc][rr]=0.f;

  const float* gW = w_out + (size_t)sdd*V_N + cb + seg*4;
  const float* gH = h2t + sdd*64 + seg*4;

  float4 wA = *(const float4*)gW;
  float4 wB = *(const float4*)(gW + (size_t)16*V_N);
  float4 hA = *(const float4*)gH;
  float4 hB = *(const float4*)(gH + 16*64);
  *(float4*)&Wt[sdd][seg*4]    = wA;
  *(float4*)&Wt[sdd+16][seg*4] = wB;
  *(float4*)&Ht[sdd][seg*4]    = hA;
  *(float4*)&Ht[sdd+16][seg*4] = hB;
  __syncthreads();

  for (int ch=0; ch<32; ++ch){
    int nxt = ch + 1;
    if (nxt < 32){   // issue next chunk's loads early; consumed after compute
      const float* gWn = gW + (size_t)nxt*32*V_N;
      const float* gHn = gH + (size_t)nxt*32*64;
      wA = *(const float4*)gWn;
      wB = *(const float4*)(gWn + (size_t)16*V_N);
      hA = *(const float4*)gHn;
      hB = *(const float4*)(gHn + 16*64);
    }
    #pragma unroll 8
    for (int dd=0; dd<32; ++dd){
      float4 w4 = *(const float4*)&Wt[dd][cx*4];
      float4 h4 = *(const float4*)&Ht[dd][ry*4];
      acc[0][0]=fmaf(w4.x,h4.x,acc[0][0]); acc[0][1]=fmaf(w4.x,h4.y,acc[0][1]);
      acc[0][2]=fmaf(w4.x,h4.z,acc[0][2]); acc[0][3]=fmaf(w4.x,h4.w,acc[0][3]);
      acc[1][0]=fmaf(w4.y,h4.x,acc[1][0]); acc[1][1]=fmaf(w4.y,h4.y,acc[1][1]);
      acc[1][2]=fmaf(w4.y,h4.z,acc[1][2]); acc[1][3]=fmaf(w4.y,h4.w,acc[1][3]);
      acc[2][0]=fmaf(w4.z,h4.x,acc[2][0]); acc[2][1]=fmaf(w4.z,h4.y,acc[2][1]);
      acc[2][2]=fmaf(w4.z,h4.z,acc[2][2]); acc[2][3]=fmaf(w4.z,h4.w,acc[2][3]);
      acc[3][0]=fmaf(w4.w,h4.x,acc[3][0]); acc[3][1]=fmaf(w4.w,h4.y,acc[3][1]);
      acc[3][2]=fmaf(w4.w,h4.z,acc[3][2]); acc[3][3]=fmaf(w4.w,h4.w,acc[3][3]);
    }
    __syncthreads();
    if (nxt < 32){
      *(float4*)&Wt[sdd][seg*4]    = wA;
      *(float4*)&Wt[sdd+16][seg*4] = wB;
      *(float4*)&Ht[sdd][seg*4]    = hA;
      *(float4*)&Ht[sdd+16][seg*4] = hB;
      __syncthreads();
    }
  }

  float4 bias = *(const float4*)&b_out[cb + cx*4];

  // per-row stats: thread owns 4 cols of rows ry*4+rr; merge across the 16
  // contiguous lanes sharing ry via shfl_xor butterfly (width 16).
  #pragma unroll
  for (int rr=0;rr<4;++rr){
    float v0 = acc[0][rr]+bias.x, v1 = acc[1][rr]+bias.y;
    float v2 = acc[2][rr]+bias.z, v3 = acc[3][rr]+bias.w;
    int   c0i = cb + cx*4;
    float tv0=-INFINITY,tv1=-INFINITY,tv2=-INFINITY,tv3=-INFINITY;
    int   ti0=0x7fffffff,ti1=0x7fffffff,ti2=0x7fffffff,ti3=0x7fffffff;
    ins4(v0,c0i+0,tv0,tv1,tv2,tv3,ti0,ti1,ti2,ti3);
    ins4(v1,c0i+1,tv0,tv1,tv2,tv3,ti0,ti1,ti2,ti3);
    ins4(v2,c0i+2,tv0,tv1,tv2,tv3,ti0,ti1,ti2,ti3);
    ins4(v3,c0i+3,tv0,tv1,tv2,tv3,ti0,ti1,ti2,ti3);
    float z = expf(v0-tv0)+expf(v1-tv0)+expf(v2-tv0)+expf(v3-tv0);
    #pragma unroll
    for (int msk=1; msk<16; msk<<=1){
      float om  = __shfl_xor(tv0, msk, 16);
      float oz  = __shfl_xor(z,   msk, 16);
      float ov1 = __shfl_xor(tv1, msk, 16);
      float ov2 = __shfl_xor(tv2, msk, 16);
      float ov3 = __shfl_xor(tv3, msk, 16);
      int   oi0 = __shfl_xor(ti0, msk, 16);
      int   oi1 = __shfl_xor(ti1, msk, 16);
      int   oi2 = __shfl_xor(ti2, msk, 16);
      int   oi3 = __shfl_xor(ti3, msk, 16);
      float M = fmaxf(tv0, om);
      z = z*expf(tv0-M) + oz*expf(om-M);
      ins4(om, oi0, tv0,tv1,tv2,tv3, ti0,ti1,ti2,ti3);
      ins4(ov1,oi1, tv0,tv1,tv2,tv3, ti0,ti1,ti2,ti3);
      ins4(ov2,oi2, tv0,tv1,tv2,tv3, ti0,ti1,ti2,ti3);
      ins4(ov3,oi3, tv0,tv1,tv2,tv3, ti0,ti1,ti2,ti3);
    }
    if (cx == 0){
      int row = ry*4 + rr;
      size_t base = (size_t)row*NB + blockIdx.x;   // [row][block]
      pm[base]=tv0; pz[base]=z;
      pv[base*4+0]=tv0; pv[base*4+1]=tv1; pv[base*4+2]=tv2; pv[base*4+3]=tv3;
      pi[base*4+0]=ti0; pi[base*4+1]=ti1; pi[base*4+2]=ti2; pi[base*4+3]=ti3;
    }
  }
}

// ---- final: reduce NB partials per row, joint top-4 per b, write out, next-x.
__global__ __launch_bounds__(256) void k_final(
    const float* __restrict__ pm, const float* __restrict__ pz,
    const float* __restrict__ pv, const int* __restrict__ pi,
    float* __restrict__ scores, int* __restrict__ out, int t,
    float* __restrict__ xn,
    const float* __restrict__ enc_inputs, const float* __restrict__ enc_outputs,
    const float* __restrict__ embed){
  int b = blockIdx.x, tid = threadIdx.x;
  __shared__ float sm[256], sz[256], stv[1024];
  __shared__ int   sti[1024];
  __shared__ float fM[KBEAM], fZ[KBEAM], fV[16];
  __shared__ int   fI[16], sw[KBEAM];
  int nk = (t==0) ? 1 : KBEAM;
  for (int k=0;k<nk;++k){
    size_t rb = (size_t)(k*B_N + b)*NB;
    float m=-INFINITY, z=0.f;
    float av0=-INFINITY,av1=-INFINITY,av2=-INFINITY,av3=-INFINITY;
    int   ai0=0x7fffffff,ai1=0x7fffffff,ai2=0x7fffffff,ai3=0x7fffffff;
    for (int p0=tid; p0<NB; p0+=256){
      size_t p = rb + p0;
      float mf = pm[p];
      float M = fmaxf(m, mf);
      z = z*expf(m-M) + pz[p]*expf(mf-M);
      m = M;
      #pragma unroll
      for (int q=0;q<4;++q)
        ins4(pv[p*4+q], pi[p*4+q], av0,av1,av2,av3, ai0,ai1,ai2,ai3);
    }
    sm[tid]=m; sz[tid]=z;
    stv[tid*4+0]=av0; stv[tid*4+1]=av1; stv[tid*4+2]=av2; stv[tid*4+3]=av3;
    sti[tid*4+0]=ai0; sti[tid*4+1]=ai1; sti[tid*4+2]=ai2; sti[tid*4+3]=ai3;
    __syncthreads();
    for (int off=128; off>0; off>>=1){
      if (tid<off){
        float ma=sm[tid], mb=sm[tid+off];
        float za=sz[tid], zb=sz[tid+off];
        float M = fmaxf(ma,mb);
        sz[tid] = za*expf(ma-M) + zb*expf(mb-M);
        sm[tid] = M;
        float bv0=stv[tid*4],bv1=stv[tid*4+1],bv2=stv[tid*4+2],bv3=stv[tid*4+3];
        int   bi0=sti[tid*4],bi1=sti[tid*4+1],bi2=sti[tid*4+2],bi3=sti[tid*4+3];
        #pragma unroll
        for (int q=0;q<4;++q)
          ins4(stv[(tid+off)*4+q], sti[(tid+off)*4+q],
               bv0,bv1,bv2,bv3, bi0,bi1,bi2,bi3);
        stv[tid*4]=bv0; stv[tid*4+1]=bv1; stv[tid*4+2]=bv2; stv[tid*4+3]=bv3;
        sti[tid*4]=bi0; sti[tid*4+1]=bi1; sti[tid*4+2]=bi2; sti[tid*4+3]=bi3;
      }
      __syncthreads();
    }
    if (tid==0){
      fM[k]=sm[0]; fZ[k]=sz[0];
      fV[k*4+0]=stv[0]; fV[k*4+1]=stv[1]; fV[k*4+2]=stv[2]; fV[k*4+3]=stv[3];
      fI[k*4+0]=sti[0]; fI[k*4+1]=sti[1]; fI[k*4+2]=sti[2]; fI[k*4+3]=sti[3];
    }
    __syncthreads();
  }
  if (tid==0){
    if (t==0){
      #pragma unroll
      for (int j=0;j<4;++j){
        float p = expf(fV[j]-fM[0])/fZ[0];
        scores[b*4+j] = p;
        out[j*(B_N*S_LEN) + b*S_LEN] = fI[j];
        sw[j] = fI[j];
      }
    } else {
      float cv[16]; int cj[16];
      for (int k=0;k<4;++k){
        float s = scores[b*4+k];
        #pragma unroll
        for (int j=0;j<4;++j){
          cv[k*4+j] = expf(fV[k*4+j]-fM[k])/fZ[k]*s;
          cj[k*4+j] = k*V_N + fI[k*4+j];
        }
      }
      bool used[16];
      for (int i=0;i<16;++i) used[i]=false;
      for (int rank=0;rank<4;++rank){
        int best=-1;
        for (int i=0;i<16;++i){
          if (used[i]) continue;
          if (best<0 || cv[i]>cv[best] || (cv[i]==cv[best] && cj[i]<cj[best])) best=i;
        }
        used[best]=true;
        out[rank*(B_N*S_LEN) + b*S_LEN + t] = cj[best];
        sw[rank] = cj[best] % V_N;
      }
    }
  }
  __syncthreads();
  if (t < S_LEN-1){
    const float* ein = enc_inputs  + (size_t)(t+1)*B_N*E_N + (size_t)b*E_N;
    const float* eo  = enc_outputs + (size_t)(t+1)*B_N*H_N + (size_t)b*H_N;
    #pragma unroll
    for (int j=0;j<KBEAM;++j){
      float* xr = xn + (size_t)(j*B_N + b)*D2;
      const float* em = embed + (size_t)sw[j]*E_N;
      xr[tid]       = em[tid];
      xr[E_N + tid] = ein[tid];
      #pragma unroll
      for (int q=0;q<4;++q) xr[2*E_N + q*256 + tid] = eo[q*256 + tid];
    }
  }
}

extern "C" void kernel_launch(void* const* d_in, const int* in_sizes, int n_in,
                              void* d_out, int out_size, void* d_ws, size_t ws_size,
                              hipStream_t stream) {
  (void)in_sizes; (void)n_in; (void)out_size; (void)ws_size;
  const float* enc_h_n     = (const float*)d_in[0];
  const float* enc_c_n     = (const float*)d_in[1];
  const float* enc_outputs = (const float*)d_in[2];
  const float* enc_inputs  = (const float*)d_in[3];
  const float* embed       = (const float*)d_in[4];
  const float* w_ih        = (const float*)d_in[5];
  const float* w_hh        = (const float*)d_in[6];
  const float* b_lstm      = (const float*)d_in[7];
  const float* w_out       = (const float*)d_in[8];
  const float* b_out       = (const float*)d_in[9];
  int* out = (int*)d_out;

  float* ws = (float*)d_ws;
  float* xA     = ws;                        // 64*2560
  float* xB     = xA + (size_t)R_N*D2;       // 64*2560
  float* cbuf   = xB + (size_t)R_N*D2;       // 64*1024
  float* h2t    = cbuf + (size_t)R_N*H_N;    // 1024*64
  float* gpart  = h2t + (size_t)H_N*R_N;     // 8*64*4096 (2,097,152 floats)
  // partial-stat buffers alias the gpart region (disjoint lifetimes within a step)
  float* pm     = gpart;                     // 64*NB
  float* pz     = pm + (size_t)R_N*NB;       // 64*NB
  float* pv     = pz + (size_t)R_N*NB;       // 64*NB*4
  int*   pi     = (int*)(pv + (size_t)R_N*NB*4); // 64*NB*4 ints
  float* scoresb= gpart + (size_t)NDS*R_N*4096;  // 64 floats, past gpart

  k_init<<<R_N, 256, 0, stream>>>(enc_h_n, enc_c_n, enc_outputs, enc_inputs, embed, xA, cbuf);

  for (int t=0; t<S_LEN; ++t){
    float* xc = (t & 1) ? xB : xA;
    float* xn = (t & 1) ? xA : xB;
    k_gates <<<dim3(64, NDS), 256, 0, stream>>>(xc, w_ih, w_hh, gpart);
    k_lstm  <<<R_N, 256, 0, stream>>>(gpart, b_lstm, cbuf, xn, h2t);
    k_logits<<<NB, 256, 0, stream>>>(h2t, w_out, b_out, pm, pz, pv, pi);
    k_final <<<B_N, 256, 0, stream>>>(pm, pz, pv, pi, scoresb, out, t, xn,
                                      enc_inputs, enc_outputs, embed);
  }
}